// Round 1
// baseline (93.588 us; speedup 1.0000x reference)
//
#include <hip/hip_runtime.h>
#include <hip/hip_bf16.h>
#include <cstdint>

#define N1 4096
#define N2 4096
#define DD 256
#define DELTA 1.0f
#define EPSN 1e-8f

#define BM 128
#define BN 128
#define BK 32

typedef __attribute__((ext_vector_type(8))) __bf16 bf16x8;
typedef __attribute__((ext_vector_type(4))) float f32x4;

typedef const __attribute__((address_space(1))) void* gptr_t;
typedef __attribute__((address_space(3))) void* lptr_t;

// Kernel 1: row-normalize fp32 -> bf16 (torch-style eps clamp), also zero the ws accumulator.
__global__ __launch_bounds__(256) void normalize_kernel(
    const float* __restrict__ mmd1, const float* __restrict__ mmd2,
    ushort* __restrict__ out1, ushort* __restrict__ out2,
    float* __restrict__ ws_sum)
{
    int row = blockIdx.x;
    const float* src;
    ushort* dst;
    if (row < N1) { src = mmd1 + (size_t)row * DD;        dst = out1 + (size_t)row * DD; }
    else          { src = mmd2 + (size_t)(row - N1) * DD; dst = out2 + (size_t)(row - N1) * DD; }

    int t = threadIdx.x;
    float x = src[t];
    float ss = x * x;
    // wave(64) reduce
    #pragma unroll
    for (int off = 32; off; off >>= 1) ss += __shfl_down(ss, off, 64);
    __shared__ float wsum[4];
    int wid = t >> 6, lane = t & 63;
    if (lane == 0) wsum[wid] = ss;
    __syncthreads();
    float tot = wsum[0] + wsum[1] + wsum[2] + wsum[3];
    float scale = 1.0f / fmaxf(sqrtf(tot), EPSN);
    __hip_bfloat16 b = __float2bfloat16(x * scale);
    dst[t] = *reinterpret_cast<const ushort*>(&b);

    if (row == 0 && t == 0) ws_sum[0] = 0.0f;
}

// Kernel 2: C = A * B^T (row-dot-row) on bf16 via MFMA, fused label-hinge + mean-sum epilogue.
// A = normalized mmd1 [4096][256] bf16, B = normalized mmd2 [4096][256] bf16.
__global__ __launch_bounds__(256) void cos_gemm_kernel(
    const ushort* __restrict__ A, const ushort* __restrict__ B,
    const int* __restrict__ lab1, const int* __restrict__ lab2,
    float* __restrict__ ws_sum)
{
    __shared__ __align__(16) ushort As[BM * BK];  // [128][32]
    __shared__ __align__(16) ushort Bs[BN * BK];  // [128][32]
    __shared__ int l1s[BM];
    __shared__ int l2s[BN];
    __shared__ float wredsum[4];

    const int row0 = blockIdx.y * BM;
    const int col0 = blockIdx.x * BN;
    const int t = threadIdx.x;
    const int lane = t & 63, wid = t >> 6;
    const int wr = wid >> 1, wc = wid & 1;   // wave -> 64x64 quadrant

    if (t < BM) l1s[t] = lab1[row0 + t];
    else        l2s[t - BM] = lab2[col0 + (t - BM)];

    f32x4 acc[4][4] = {};

    for (int k0 = 0; k0 < DD; k0 += BK) {
        __syncthreads();  // previous compute done before overwriting LDS
        #pragma unroll
        for (int it = 0; it < 2; ++it) {
            int t2 = t + it * 256;
            int r = t2 >> 2;            // 0..127
            int c = (t2 & 3) * 8;       // 0,8,16,24  (bf16 elems)
            __builtin_amdgcn_global_load_lds(
                (gptr_t)(A + (size_t)(row0 + r) * DD + k0 + c),
                (lptr_t)(&As[r * BK + c]), 16, 0, 0);
            __builtin_amdgcn_global_load_lds(
                (gptr_t)(B + (size_t)(col0 + r) * DD + k0 + c),
                (lptr_t)(&Bs[r * BK + c]), 16, 0, 0);
        }
        __syncthreads();  // staging complete

        bf16x8 af[4], bfr[4];
        const int krow = (lane >> 4) * 8;   // k offset within BK
        const int rsel = lane & 15;         // row/col within 16
        #pragma unroll
        for (int m = 0; m < 4; ++m)
            af[m] = *reinterpret_cast<const bf16x8*>(&As[(wr * 64 + m * 16 + rsel) * BK + krow]);
        #pragma unroll
        for (int n = 0; n < 4; ++n)
            bfr[n] = *reinterpret_cast<const bf16x8*>(&Bs[(wc * 64 + n * 16 + rsel) * BK + krow]);
        #pragma unroll
        for (int m = 0; m < 4; ++m)
            #pragma unroll
            for (int n = 0; n < 4; ++n)
                acc[m][n] = __builtin_amdgcn_mfma_f32_16x16x32_bf16(af[m], bfr[n], acc[m][n], 0, 0, 0);
    }

    // Epilogue: C/D mapping col = lane&15, row = (lane>>4)*4 + reg
    float lsum = 0.0f;
    const int csel = lane & 15;
    const int rbase = (lane >> 4) * 4;
    #pragma unroll
    for (int n = 0; n < 4; ++n) {
        int j = wc * 64 + n * 16 + csel;
        int l2 = l2s[j];
        #pragma unroll
        for (int m = 0; m < 4; ++m) {
            #pragma unroll
            for (int e = 0; e < 4; ++e) {
                int i = wr * 64 + m * 16 + rbase + e;
                float cosv = acc[m][n][e];
                float v = (l1s[i] == l2) ? fmaxf(DELTA - cosv, 0.0f) : cosv;
                lsum += v;
            }
        }
    }
    #pragma unroll
    for (int off = 32; off; off >>= 1) lsum += __shfl_down(lsum, off, 64);
    if (lane == 0) wredsum[wid] = lsum;
    __syncthreads();
    if (t == 0) atomicAdd(ws_sum, wredsum[0] + wredsum[1] + wredsum[2] + wredsum[3]);
}

__global__ void finalize_kernel(const float* __restrict__ ws_sum, float* __restrict__ out) {
    out[0] = ws_sum[0] * (1.0f / ((float)N1 * (float)N2));
}

extern "C" void kernel_launch(void* const* d_in, const int* in_sizes, int n_in,
                              void* d_out, int out_size, void* d_ws, size_t ws_size,
                              hipStream_t stream) {
    const float* mmd1 = (const float*)d_in[0];
    const float* mmd2 = (const float*)d_in[1];
    const int* lab1 = (const int*)d_in[2];
    const int* lab2 = (const int*)d_in[3];

    ushort* n1b = (ushort*)d_ws;                       // 4096*256*2 = 2 MB
    ushort* n2b = n1b + (size_t)N1 * DD;               // 2 MB
    float* ws_sum = (float*)((char*)d_ws + (size_t)(N1 + N2) * DD * 2);
    float* out = (float*)d_out;

    normalize_kernel<<<N1 + N2, 256, 0, stream>>>(mmd1, mmd2, n1b, n2b, ws_sum);
    cos_gemm_kernel<<<dim3(BN / 4, BM / 4) /*unused*/, 256, 0, stream>>>(n1b, n2b, lab1, lab2, ws_sum);
    // NOTE: grid must be (N2/BN, N1/BM) = (32, 32)
    finalize_kernel<<<1, 1, 0, stream>>>(ws_sum, out);
}

// Round 2
// 87.949 us; speedup vs baseline: 1.0641x; 1.0641x over previous
//
#include <hip/hip_runtime.h>
#include <hip/hip_bf16.h>
#include <cstdint>

#define N1 4096
#define N2 4096
#define DD 256
#define DELTA 1.0f
#define EPSN 1e-8f

#define BM 128
#define BN 128
#define BK 64

typedef __attribute__((ext_vector_type(8))) __bf16 bf16x8;
typedef __attribute__((ext_vector_type(4))) float f32x4;

typedef const __attribute__((address_space(1))) void* gptr_t;
typedef __attribute__((address_space(3))) void* lptr_t;

// Kernel 1: row-normalize fp32 -> bf16 (torch-style eps clamp), float4-vectorized.
// One wave per row, 4 rows per block. Also zeroes the ws accumulator.
__global__ __launch_bounds__(256) void normalize_kernel(
    const float* __restrict__ mmd1, const float* __restrict__ mmd2,
    ushort* __restrict__ out1, ushort* __restrict__ out2,
    float* __restrict__ ws_sum)
{
    const int wid = threadIdx.x >> 6, lane = threadIdx.x & 63;
    const int row = blockIdx.x * 4 + wid;

    const float* srcp;
    ushort* dstp;
    if (row < N1) { srcp = mmd1 + (size_t)row * DD;        dstp = out1 + (size_t)row * DD; }
    else          { srcp = mmd2 + (size_t)(row - N1) * DD; dstp = out2 + (size_t)(row - N1) * DD; }

    float4 v = reinterpret_cast<const float4*>(srcp)[lane];
    float ss = v.x * v.x + v.y * v.y + v.z * v.z + v.w * v.w;
    #pragma unroll
    for (int off = 32; off; off >>= 1) ss += __shfl_xor(ss, off, 64);  // butterfly: all lanes get total
    float scale = 1.0f / fmaxf(sqrtf(ss), EPSN);

    __hip_bfloat16 b0 = __float2bfloat16(v.x * scale);
    __hip_bfloat16 b1 = __float2bfloat16(v.y * scale);
    __hip_bfloat16 b2 = __float2bfloat16(v.z * scale);
    __hip_bfloat16 b3 = __float2bfloat16(v.w * scale);
    ushort4 o;
    o.x = *reinterpret_cast<const ushort*>(&b0);
    o.y = *reinterpret_cast<const ushort*>(&b1);
    o.z = *reinterpret_cast<const ushort*>(&b2);
    o.w = *reinterpret_cast<const ushort*>(&b3);
    reinterpret_cast<ushort4*>(dstp)[lane] = o;

    if (blockIdx.x == 0 && threadIdx.x == 0) ws_sum[0] = 0.0f;
}

// Kernel 2: C = A * B^T on bf16 via MFMA, fused label-hinge + mean-sum epilogue.
// LDS tiles are chunk-swizzled: row r's 16B-chunk at LDS position c holds global
// chunk (c ^ (r&7)). Staging keeps the LDS destination linear (global_load_lds
// requirement) and pre-swizzles the GLOBAL source; reads apply the same XOR.
__global__ __launch_bounds__(256) void cos_gemm_kernel(
    const ushort* __restrict__ A, const ushort* __restrict__ B,
    const int* __restrict__ lab1, const int* __restrict__ lab2,
    float* __restrict__ ws_sum)
{
    __shared__ __align__(16) ushort As[BM * BK];  // 16 KB, rows of 64 elems = 8 chunks
    __shared__ __align__(16) ushort Bs[BN * BK];  // 16 KB
    __shared__ int l1s[BM];
    __shared__ int l2s[BN];
    __shared__ float wredsum[4];

    const int row0 = blockIdx.y * BM;
    const int col0 = blockIdx.x * BN;
    const int t = threadIdx.x;
    const int lane = t & 63, wid = t >> 6;
    const int wr = wid >> 1, wc = wid & 1;   // wave -> 64x64 quadrant

    if (t < BM) l1s[t] = lab1[row0 + t];
    else        l2s[t - BM] = lab2[col0 + (t - BM)];

    f32x4 acc[4][4] = {};

    for (int k0 = 0; k0 < DD; k0 += BK) {
        __syncthreads();  // previous compute done before overwriting LDS
        // Stage A and B tiles: 128 rows x 64 elems x 2B = 16 KB each = 1024 chunks of 16B.
        // 4 iterations x 256 threads per matrix.
        #pragma unroll
        for (int it = 0; it < 4; ++it) {
            int idx = t + it * 256;          // 0..1023 chunk index
            int r = idx >> 3;                // 0..127
            int c = idx & 7;                 // LDS chunk position
            int gc = c ^ (r & 7);            // swizzled global chunk
            __builtin_amdgcn_global_load_lds(
                (gptr_t)(A + (size_t)(row0 + r) * DD + k0 + gc * 8),
                (lptr_t)(&As[r * BK + c * 8]), 16, 0, 0);
            __builtin_amdgcn_global_load_lds(
                (gptr_t)(B + (size_t)(col0 + r) * DD + k0 + gc * 8),
                (lptr_t)(&Bs[r * BK + c * 8]), 16, 0, 0);
        }
        __syncthreads();  // staging complete

        #pragma unroll
        for (int kk = 0; kk < 2; ++kk) {     // two 32-wide K substeps
            const int ck = kk * 4 + (lane >> 4);   // chunk within row for this frag
            const int rsel = lane & 15;
            bf16x8 af[4], bfr[4];
            #pragma unroll
            for (int m = 0; m < 4; ++m) {
                int R = wr * 64 + m * 16 + rsel;
                af[m] = *reinterpret_cast<const bf16x8*>(&As[R * BK + (ck ^ (R & 7)) * 8]);
            }
            #pragma unroll
            for (int n = 0; n < 4; ++n) {
                int R = wc * 64 + n * 16 + rsel;
                bfr[n] = *reinterpret_cast<const bf16x8*>(&Bs[R * BK + (ck ^ (R & 7)) * 8]);
            }
            #pragma unroll
            for (int m = 0; m < 4; ++m)
                #pragma unroll
                for (int n = 0; n < 4; ++n)
                    acc[m][n] = __builtin_amdgcn_mfma_f32_16x16x32_bf16(af[m], bfr[n], acc[m][n], 0, 0, 0);
        }
    }

    // Epilogue: C/D mapping col = lane&15, row = (lane>>4)*4 + reg  (m89)
    float lsum = 0.0f;
    const int csel = lane & 15;
    #pragma unroll
    for (int n = 0; n < 4; ++n) {
        int j = wc * 64 + n * 16 + csel;
        int l2 = l2s[j];
        #pragma unroll
        for (int m = 0; m < 4; ++m) {
            int ibase = wr * 64 + m * 16 + (lane >> 4) * 4;
            #pragma unroll
            for (int e = 0; e < 4; ++e) {
                float cosv = acc[m][n][e];
                float v = (l1s[ibase + e] == l2) ? fmaxf(DELTA - cosv, 0.0f) : cosv;
                lsum += v;
            }
        }
    }
    #pragma unroll
    for (int off = 32; off; off >>= 1) lsum += __shfl_down(lsum, off, 64);
    if (lane == 0) wredsum[wid] = lsum;
    __syncthreads();
    if (t == 0) atomicAdd(ws_sum, wredsum[0] + wredsum[1] + wredsum[2] + wredsum[3]);
}

__global__ void finalize_kernel(const float* __restrict__ ws_sum, float* __restrict__ out) {
    out[0] = ws_sum[0] * (1.0f / ((float)N1 * (float)N2));
}

extern "C" void kernel_launch(void* const* d_in, const int* in_sizes, int n_in,
                              void* d_out, int out_size, void* d_ws, size_t ws_size,
                              hipStream_t stream) {
    const float* mmd1 = (const float*)d_in[0];
    const float* mmd2 = (const float*)d_in[1];
    const int* lab1 = (const int*)d_in[2];
    const int* lab2 = (const int*)d_in[3];

    ushort* n1b = (ushort*)d_ws;                       // 4096*256*2 = 2 MB
    ushort* n2b = n1b + (size_t)N1 * DD;               // 2 MB
    float* ws_sum = (float*)((char*)d_ws + (size_t)(N1 + N2) * DD * 2);
    float* out = (float*)d_out;

    normalize_kernel<<<(N1 + N2) / 4, 256, 0, stream>>>(mmd1, mmd2, n1b, n2b, ws_sum);
    cos_gemm_kernel<<<dim3(N2 / BN, N1 / BM), 256, 0, stream>>>(n1b, n2b, lab1, lab2, ws_sum);
    finalize_kernel<<<1, 1, 0, stream>>>(ws_sum, out);
}